// Round 13
// baseline (2196.074 us; speedup 1.0000x reference)
//
#include <hip/hip_runtime.h>
#include <hip/hip_bf16.h>
#include <stdint.h>

// ---------------- problem constants ----------------
constexpr int E   = 384;
constexpr int DFF = 1536;
constexpr int NH  = 6;
constexpr int HD  = 64;
constexpr int T   = 256;
constexpr int NL  = 6;
constexpr int NV  = 65;
constexpr int BB  = 128;
constexpr int MTOT = BB * T;           // 32768 rows
constexpr int CB  = 32;                // (kept for ws layout compatibility)

typedef __bf16 bf16;
typedef __attribute__((ext_vector_type(8))) __bf16 bf16x8;
typedef __attribute__((ext_vector_type(4))) float floatx4;

// ---------------- generic bf16 GEMM: C = A[M,K] @ Bt[N,K]^T ----------------
// Two-step staging pipeline (prefetch distance 2): reg-load tile k+2,
// ds_write tile k+1, compute tile k from LDS. 64 B LDS row stride (80 B pad
// regressed: bank conflicts doubled — measured r12).
// LNA: apply per-row LayerNorm (stats in lnst, affine lng/lnb) to A during
// staging — replaces the standalone LN kernel.
// MODE 0: bf16 out (+bias opt, +relu opt, N-mask via Nvalid)
// MODE 1: bf16 residual in-place: C[r,c] += acc + bias
// MODE 4: f32 out with bias + N-mask (final logits)
// MODE 5: fused QKV: cols 0..767 -> qk row-major (ld 768); cols 768..1151 ->
//         vt[(row>>8)*(E*T) + (col-768)*T + (row&255)]  (V transposed store)
#define GBM 128
#define GBN 128
#define GBK 32

template <int MODE, bool LNA>
__global__ __launch_bounds__(256) void k_gemm(
    const bf16* __restrict__ A, long sAb, long sAh, int lda,
    const bf16* __restrict__ Bt, long sBb, long sBh, int ldb,
    const float* __restrict__ bias,
    void* __restrict__ Cv, void* __restrict__ Cv2, long sCb, long sCh, int ldc,
    int Mtiles, int Ntiles, int Nvalid, int K,
    int bdiv, float scale, int relu,
    const float2* __restrict__ lnst, const float* __restrict__ lng,
    const float* __restrict__ lnb)
{
    __shared__ __align__(16) bf16 As[2 * GBM * GBK];   // 2 x 8 KB
    __shared__ __align__(16) bf16 Bs[2 * GBN * GBK];

    // XCD swizzle: all N-tiles of an M-tile land on one XCD's L2.
    int nb = gridDim.x;
    int per = nb >> 3;
    int bphys = blockIdx.x;
    int bid = (bphys & 7) * per + (bphys >> 3);

    int nt = bid % Ntiles; bid /= Ntiles;
    int mt = bid % Mtiles;
    int bat = bid / Mtiles;
    int bb = bat / bdiv, bh = bat - bb * bdiv;

    const bf16* Ab = A + (long)bb * sAb + (long)bh * sAh + (long)mt * GBM * lda;
    const bf16* Bb = Bt + (long)bb * sBb + (long)bh * sBh + (long)nt * GBN * ldb;

    int tid = threadIdx.x;
    int lane = tid & 63;
    int wid = tid >> 6;
    int wm = wid >> 1, wn = wid & 1;
    int lq = lane >> 4, lr = lane & 15;

    int srow = tid >> 2;            // 0..63
    int skc  = (tid & 3) * 8;       // k element offset 0,8,16,24

    const bf16* Arow = Ab + (long)srow * lda + skc;
    const bf16* Brow = Bb + (long)srow * ldb + skc;
    const long a2 = 64 * (long)lda;
    const long b2 = 64 * (long)ldb;

    char* AsB = (char*)As;
    char* BsB = (char*)Bs;

    // per-row LN constants (rows fixed per thread; batch==1 for LNA kernels)
    float c00 = 0.f, c01 = 1.f, c10 = 0.f, c11 = 1.f;
    if (LNA) {
        int grow = mt * GBM + srow;
        float2 s0v = lnst[grow];
        float2 s1v = lnst[grow + 64];
        c00 = s0v.x; c01 = s0v.y; c10 = s1v.x; c11 = s1v.y;
    }

    // transform helper: v = (v*c1 + c0) * g[k] + b[k]
    auto xf = [&](bf16x8 a, float c0, float c1, int kb) -> bf16x8 {
        if (!LNA) return a;
        bf16x8 r;
#pragma unroll
        for (int j = 0; j < 8; j++) {
            float v = (float)a[j];
            v = v * c1 + c0;
            v = v * lng[kb + j] + lnb[kb + j];
            r[j] = (bf16)v;
        }
        return r;
    };

    floatx4 zero = {0.f, 0.f, 0.f, 0.f};
    floatx4 acc[4][4];
#pragma unroll
    for (int i = 0; i < 4; i++)
#pragma unroll
        for (int j = 0; j < 4; j++) acc[i][j] = zero;

    int nk = K / GBK;

    // prologue: tile0 -> regs -> buf0; tile1 -> regs
    bf16x8 ra0 = *(const bf16x8*)(Arow);
    bf16x8 ra1 = *(const bf16x8*)(Arow + a2);
    bf16x8 rb0 = *(const bf16x8*)(Brow);
    bf16x8 rb1 = *(const bf16x8*)(Brow + b2);
    *(bf16x8*)(AsB + tid * 16)        = xf(ra0, c00, c01, skc);
    *(bf16x8*)(AsB + 4096 + tid * 16) = xf(ra1, c10, c11, skc);
    *(bf16x8*)(BsB + tid * 16)        = rb0;
    *(bf16x8*)(BsB + 4096 + tid * 16) = rb1;
    if (nk > 1) {
        ra0 = *(const bf16x8*)(Arow + GBK);
        ra1 = *(const bf16x8*)(Arow + a2 + GBK);
        rb0 = *(const bf16x8*)(Brow + GBK);
        rb1 = *(const bf16x8*)(Brow + b2 + GBK);
    }
    __syncthreads();

    for (int ki = 0; ki < nk; ki++) {
        int ib = ki & 1;
        if (ki + 1 < nk) {
            int kb = (ki + 1) * GBK + skc;
            char* An = AsB + (1 - ib) * 8192;
            char* Bn = BsB + (1 - ib) * 8192;
            *(bf16x8*)(An + tid * 16)        = xf(ra0, c00, c01, kb);
            *(bf16x8*)(An + 4096 + tid * 16) = xf(ra1, c10, c11, kb);
            *(bf16x8*)(Bn + tid * 16)        = rb0;
            *(bf16x8*)(Bn + 4096 + tid * 16) = rb1;
        }
        if (ki + 2 < nk) {
            int koff = (ki + 2) * GBK;
            ra0 = *(const bf16x8*)(Arow + koff);
            ra1 = *(const bf16x8*)(Arow + a2 + koff);
            rb0 = *(const bf16x8*)(Brow + koff);
            rb1 = *(const bf16x8*)(Brow + b2 + koff);
        }
        char* Ac = AsB + ib * 8192;
        char* Bc = BsB + ib * 8192;

        bf16x8 af[4], bfr[4];
#pragma unroll
        for (int mi = 0; mi < 4; mi++)
            af[mi] = *(const bf16x8*)(Ac + ((wm * 64 + mi * 16 + lr) * GBK + lq * 8) * 2);
#pragma unroll
        for (int ni = 0; ni < 4; ni++)
            bfr[ni] = *(const bf16x8*)(Bc + ((wn * 64 + ni * 16 + lr) * GBK + lq * 8) * 2);
#pragma unroll
        for (int mi = 0; mi < 4; mi++)
#pragma unroll
            for (int ni = 0; ni < 4; ni++)
                acc[mi][ni] = __builtin_amdgcn_mfma_f32_16x16x32_bf16(
                    af[mi], bfr[ni], acc[mi][ni], 0, 0, 0);
        __syncthreads();
    }

    int m0 = mt * GBM, n0 = nt * GBN;
#pragma unroll
    for (int mi = 0; mi < 4; mi++) {
#pragma unroll
        for (int ni = 0; ni < 4; ni++) {
            int colL = n0 + wn * 64 + ni * 16 + lr;
#pragma unroll
            for (int r = 0; r < 4; r++) {
                int rowL = m0 + wm * 64 + mi * 16 + lq * 4 + r;
                float val = acc[mi][ni][r];
                if (MODE == 5) {
                    val += bias[colL];
                    if (colL < 768) {
                        bf16* Cp = (bf16*)Cv;
                        Cp[(long)rowL * 768 + colL] = (bf16)val;
                    } else {
                        bf16* Cp = (bf16*)Cv2;
                        long addr = (long)(rowL >> 8) * (E * T) + (long)(colL - 768) * T + (rowL & 255);
                        Cp[addr] = (bf16)val;
                    }
                } else if (MODE == 1) {
                    bf16* Cp = (bf16*)Cv;
                    long idx = (long)rowL * ldc + colL;
                    Cp[idx] = (bf16)((float)Cp[idx] + val + bias[colL]);
                } else if (MODE == 4) {
                    if (colL < Nvalid) {
                        float* Cp = (float*)Cv;
                        Cp[(long)rowL * ldc + colL] = val + bias[colL];
                    }
                } else {
                    if (colL < Nvalid) {
                        if (bias) val += bias[colL];
                        if (relu) val = fmaxf(val, 0.f);
                        bf16* Cp = (bf16*)Cv + (long)bb * sCb + (long)bh * sCh;
                        Cp[(long)rowL * ldc + colL] = (bf16)val;
                    }
                }
            }
        }
    }
}

// ---------------- fused causal attention (LDS-staged K/V) ----------------
__global__ __launch_bounds__(256) void k_attn(
    const bf16* __restrict__ qk, const bf16* __restrict__ vt,
    bf16* __restrict__ o)
{
    int nb = gridDim.x;
    int per = nb >> 3;
    int bphys = blockIdx.x;
    int bid = (bphys & 7) * per + (bphys >> 3);

    int qt = bid & 3; bid >>= 2;
    int h = bid % NH; int b = bid / NH;
    int tid = threadIdx.x;
    int lane = tid & 63;
    int w = tid >> 6;
    int lq = lane >> 4;     // 0..3
    int lr = lane & 15;

    __shared__ __align__(16) bf16 Ks[256 * 72];   // K rows padded; reused for P
    __shared__ __align__(16) bf16 Vs[64 * 264];   // V^T rows padded

    const bf16* qbase = qk + (long)(b * T + qt * 64 + w * 16) * 768 + h * 64;
    const bf16* kbase = qk + (long)(b * T) * 768 + 384 + h * 64;
    const bf16* vbase = vt + ((long)b * E + h * 64) * T;

#pragma unroll
    for (int i = 0; i < 8; i++) {
        int idx = i * 256 + tid;
        int row = idx >> 3, off = (idx & 7) * 8;
        *(bf16x8*)(&Ks[row * 72 + off]) = *(const bf16x8*)(kbase + (long)row * 768 + off);
    }
#pragma unroll
    for (int i = 0; i < 8; i++) {
        int idx = i * 256 + tid;
        int row = idx >> 5, off = (idx & 31) * 8;
        *(bf16x8*)(&Vs[row * 264 + off]) = *(const bf16x8*)(vbase + (long)row * 256 + off);
    }

    bf16x8 aq0 = *(const bf16x8*)(qbase + (long)lr * 768 + lq * 8);
    bf16x8 aq1 = *(const bf16x8*)(qbase + (long)lr * 768 + 32 + lq * 8);

    __syncthreads();

    const int ntmax = qt * 4 + 3;
    floatx4 zero = {0.f, 0.f, 0.f, 0.f};
    floatx4 s[16];
#pragma unroll
    for (int nt = 0; nt < 16; nt++) s[nt] = zero;

#pragma unroll
    for (int nt = 0; nt < 16; nt++) {
        if (nt <= ntmax) {
            const bf16* kp = &Ks[(nt * 16 + lr) * 72 + lq * 8];
            bf16x8 b0 = *(const bf16x8*)(kp);
            bf16x8 b1 = *(const bf16x8*)(kp + 32);
            s[nt] = __builtin_amdgcn_mfma_f32_16x16x32_bf16(aq0, b0, s[nt], 0, 0, 0);
            s[nt] = __builtin_amdgcn_mfma_f32_16x16x32_bf16(aq1, b1, s[nt], 0, 0, 0);
        }
    }

    int trow0 = qt * 64 + w * 16 + lq * 4;
    float m4[4] = {-3e38f, -3e38f, -3e38f, -3e38f};
#pragma unroll
    for (int nt = 0; nt < 16; nt++) {
        if (nt <= ntmax) {
            int tc = nt * 16 + lr;
#pragma unroll
            for (int r = 0; r < 4; r++) {
                float v = s[nt][r] * 0.125f;
                if (tc > trow0 + r) v = -3e38f;
                s[nt][r] = v;
                m4[r] = fmaxf(m4[r], v);
            }
        }
    }
#pragma unroll
    for (int r = 0; r < 4; r++) {
#pragma unroll
        for (int off = 1; off < 16; off <<= 1)
            m4[r] = fmaxf(m4[r], __shfl_xor(m4[r], off, 64));
    }

    float l4[4] = {0.f, 0.f, 0.f, 0.f};
#pragma unroll
    for (int nt = 0; nt < 16; nt++) {
        if (nt <= ntmax) {
#pragma unroll
            for (int r = 0; r < 4; r++) {
                float pv = __expf(s[nt][r] - m4[r]);
                l4[r] += pv;
                s[nt][r] = pv;
            }
        }
    }
#pragma unroll
    for (int r = 0; r < 4; r++) {
#pragma unroll
        for (int off = 1; off < 16; off <<= 1)
            l4[r] += __shfl_xor(l4[r], off, 64);
    }

    __syncthreads();   // Ks fully consumed -> reuse for P

    bf16* P = Ks + w * (16 * 264);
#pragma unroll
    for (int nt = 0; nt < 16; nt++) {
        if (nt <= ntmax) {
#pragma unroll
            for (int r = 0; r < 4; r++)
                P[(lq * 4 + r) * 264 + nt * 16 + lr] = (bf16)s[nt][r];
        }
    }

    floatx4 oacc[4];
#pragma unroll
    for (int nd = 0; nd < 4; nd++) oacc[nd] = zero;
    const int kkmax = 2 * (qt + 1);
#pragma unroll
    for (int kk = 0; kk < 8; kk++) {
        if (kk < kkmax) {
            bf16x8 ap = *(const bf16x8*)(&P[lr * 264 + kk * 32 + lq * 8]);
#pragma unroll
            for (int nd = 0; nd < 4; nd++) {
                bf16x8 bv = *(const bf16x8*)(&Vs[(nd * 16 + lr) * 264 + kk * 32 + lq * 8]);
                oacc[nd] = __builtin_amdgcn_mfma_f32_16x16x32_bf16(ap, bv, oacc[nd], 0, 0, 0);
            }
        }
    }

#pragma unroll
    for (int r = 0; r < 4; r++) {
        float inv = 1.0f / l4[r];
        long rowg = (long)b * T + trow0 + r;
#pragma unroll
        for (int nd = 0; nd < 4; nd++) {
            o[rowg * E + h * 64 + nd * 16 + lr] = (bf16)(oacc[nd][r] * inv);
        }
    }
}

// ---------------- LN row stats: c0 = -mu*rs, c1 = rs (wave per row) ----------------
__global__ void k_lnstats(const bf16* __restrict__ x, float2* __restrict__ st) {
    int row = blockIdx.x * 4 + (threadIdx.x >> 6);
    int lane = threadIdx.x & 63;
    const bf16* xr = x + (long)row * E;
    float v[6];
    float s = 0.f;
#pragma unroll
    for (int i = 0; i < 6; i++) { v[i] = (float)xr[lane + 64 * i]; s += v[i]; }
#pragma unroll
    for (int o = 1; o < 64; o <<= 1) s += __shfl_xor(s, o, 64);
    float mu = s * (1.0f / E);
    float q = 0.f;
#pragma unroll
    for (int i = 0; i < 6; i++) { float d = v[i] - mu; q += d * d; }
#pragma unroll
    for (int o = 1; o < 64; o <<= 1) q += __shfl_xor(q, o, 64);
    float rs = rsqrtf(q * (1.0f / E) + 1e-5f);
    if (lane == 0) st[row] = make_float2(-mu * rs, rs);
}

// ---------------- weight transpose f32 -> bf16 (+zero-pad rows) ----------------
__global__ void k_transpose(const float* __restrict__ W, bf16* __restrict__ Wt,
                            int K, int N, int NPAD) {
    long idx = (long)blockIdx.x * 256 + threadIdx.x;
    long per = (long)NPAD * K;
    int l = (int)(idx / per);
    long r = idx - (long)l * per;
    int n = (int)(r / K);
    int k = (int)(r - (long)n * K);
    Wt[idx] = (n < N) ? (bf16)W[((long)l * K + k) * N + n] : (bf16)0.0f;
}

// ---------------- fused QKV weight transpose: [L][1152][384] ----------------
__global__ void k_transpose_qkv(const float* __restrict__ Wq, const float* __restrict__ Wk,
                                const float* __restrict__ Wv, bf16* __restrict__ Wt) {
    long idx = (long)blockIdx.x * 256 + threadIdx.x;
    long per = (long)1152 * E;
    int l = (int)(idx / per);
    long r = idx - (long)l * per;
    int n = (int)(r / E);
    int k = (int)(r - (long)n * E);
    const float* src;
    int nn;
    if (n < 384)      { src = Wq; nn = n; }
    else if (n < 768) { src = Wk; nn = n - 384; }
    else              { src = Wv; nn = n - 768; }
    Wt[idx] = (bf16)src[((long)l * E + k) * E + nn];
}

// ---------------- fused QKV bias concat: [L][1152] f32 ----------------
__global__ void k_bias_qkv(const float* __restrict__ bq, const float* __restrict__ bk,
                           const float* __restrict__ bv, float* __restrict__ bqkv) {
    int idx = blockIdx.x * 256 + threadIdx.x;
    int l = idx / 1152;
    int j = idx - l * 1152;
    const float* src;
    int jj;
    if (j < 384)      { src = bq; jj = j; }
    else if (j < 768) { src = bk; jj = j - 384; }
    else              { src = bv; jj = j - 768; }
    bqkv[idx] = src[l * E + jj];
}

// ---------------- embedding + positional -> bf16 residual ----------------
__global__ void k_embed(const int* __restrict__ tokens, const float* __restrict__ pos,
                        const float* __restrict__ emb, bf16* __restrict__ x) {
    long idx = (long)blockIdx.x * 256 + threadIdx.x;
    int e = (int)(idx % E);
    long bt = idx / E;
    int t = (int)(bt % T);
    int tok = tokens[bt];
    x[idx] = (bf16)(emb[(long)tok * E + e] + pos[(long)t * E + e]);
}

// ---------------- launcher ----------------
extern "C" void kernel_launch(void* const* d_in, const int* in_sizes, int n_in,
                              void* d_out, int out_size, void* d_ws, size_t ws_size,
                              hipStream_t stream) {
    const int*   tokens = (const int*)d_in[0];
    const float* pos  = (const float*)d_in[1];
    const float* emb  = (const float*)d_in[2];
    const float* Wq   = (const float*)d_in[3];
    const float* bq   = (const float*)d_in[4];
    const float* Wk   = (const float*)d_in[5];
    const float* bk   = (const float*)d_in[6];
    const float* Wv   = (const float*)d_in[7];
    const float* bv   = (const float*)d_in[8];
    const float* Wo   = (const float*)d_in[9];
    const float* bo   = (const float*)d_in[10];
    const float* g1   = (const float*)d_in[11];
    const float* be1  = (const float*)d_in[12];
    const float* W1   = (const float*)d_in[13];
    const float* c1   = (const float*)d_in[14];
    const float* W2   = (const float*)d_in[15];
    const float* c2   = (const float*)d_in[16];
    const float* g2   = (const float*)d_in[17];
    const float* be2  = (const float*)d_in[18];
    const float* Wl   = (const float*)d_in[19];
    const float* bl   = (const float*)d_in[20];

    // ---- workspace layout (~173 MB peak) ----
    char* p = (char*)d_ws;
    bf16* x  = (bf16*)p;   p += (long)MTOT * E * 2;          // residual (bf16)
    bf16* h  = (bf16*)p;   p += (long)MTOT * E * 2;          // o buffer
    bf16* qk = (bf16*)p;   p += (long)MTOT * 768 * 2;        // fused Q|K
    bf16* vt = (bf16*)p;   p += (long)BB * E * T * 2;        // V^T per (seq,head)
    bf16* SP = (bf16*)p;   p += (long)CB * NH * T * T * 2;   // kept only for mid alias span
    bf16* WqkvT = (bf16*)p; p += (long)NL * 1152 * E * 2;
    bf16* WoT = (bf16*)p;  p += (long)NL * E * E * 2;
    bf16* W1T = (bf16*)p;  p += (long)NL * DFF * E * 2;
    bf16* W2T = (bf16*)p;  p += (long)NL * E * DFF * 2;
    bf16* WlT = (bf16*)p;  p += (long)128 * E * 2;
    float* bqkv = (float*)p; p += (long)NL * 1152 * 4;
    float2* lnst = (float2*)p; p += (long)MTOT * 8;          // LN stats (256 KB)
    bf16* mid = qk;          // alias: qk+vt+SP = 100.66 MB = MTOT*DFF*2 exactly
    bf16* o   = h;
    (void)SP;

    // ---- setup (once per call) ----
    k_transpose_qkv<<<(NL * 1152 * E) / 256, 256, 0, stream>>>(Wq, Wk, Wv, WqkvT);
    k_transpose<<<(NL * E * E) / 256, 256, 0, stream>>>(Wo, WoT, E, E, E);
    k_transpose<<<(NL * DFF * E) / 256, 256, 0, stream>>>(W1, W1T, E, DFF, DFF);
    k_transpose<<<(NL * E * DFF) / 256, 256, 0, stream>>>(W2, W2T, DFF, E, E);
    k_transpose<<<(128 * E) / 256, 256, 0, stream>>>(Wl, WlT, E, NV, 128);
    k_bias_qkv<<<(NL * 1152) / 256, 256, 0, stream>>>(bq, bk, bv, bqkv);

    // ---- embedding ----
    k_embed<<<(MTOT * E) / 256, 256, 0, stream>>>(tokens, pos, emb, x);

    for (int l = 0; l < NL; l++) {
        // LN1 stats
        k_lnstats<<<MTOT / 4, 256, 0, stream>>>(x, lnst);
        // fused LN1 + QKV: M=32768, N=1152, K=384
        k_gemm<5, true><<<256 * 9, 256, 0, stream>>>(x, 0, 0, E, WqkvT + (long)l * 1152 * E, 0, 0, E,
                                                     bqkv + l * 1152, qk, vt, 0, 0, 0,
                                                     256, 9, 1152, E, 1, 1.0f, 0,
                                                     lnst, g1 + l * E, be1 + l * E);
        // fused causal attention
        k_attn<<<BB * NH * 4, 256, 0, stream>>>(qk, vt, o);
        // x += O @ Wo + bo
        k_gemm<1, false><<<256 * 3, 256, 0, stream>>>(o, 0, 0, E, WoT + (long)l * E * E, 0, 0, E,
                                                      bo + l * E, x, nullptr, 0, 0, E,
                                                      256, 3, E, E, 1, 1.0f, 0,
                                                      nullptr, nullptr, nullptr);
        // LN2 stats
        k_lnstats<<<MTOT / 4, 256, 0, stream>>>(x, lnst);
        // fused LN2 + FFN1: mid = relu(ln2(x) @ W1 + c1)
        k_gemm<0, true><<<256 * 12, 256, 0, stream>>>(x, 0, 0, E, W1T + (long)l * DFF * E, 0, 0, E,
                                                      c1 + l * DFF, mid, nullptr, 0, 0, DFF,
                                                      256, 12, DFF, E, 1, 1.0f, 1,
                                                      lnst, g2 + l * E, be2 + l * E);
        // x += mid @ W2 + c2
        k_gemm<1, false><<<256 * 3, 256, 0, stream>>>(mid, 0, 0, DFF, W2T + (long)l * E * DFF, 0, 0, DFF,
                                                      c2 + l * E, x, nullptr, 0, 0, E,
                                                      256, 3, E, DFF, 1, 1.0f, 0,
                                                      nullptr, nullptr, nullptr);
    }

    // logits = x @ Wl + bl  (N=65 masked from 128), f32 out
    k_gemm<4, false><<<256 * 1, 256, 0, stream>>>(x, 0, 0, E, WlT, 0, 0, E,
                                                  bl, d_out, nullptr, 0, 0, NV,
                                                  256, 1, NV, E, 1, 1.0f, 0,
                                                  nullptr, nullptr, nullptr);
}

// Round 14
// 2096.590 us; speedup vs baseline: 1.0475x; 1.0475x over previous
//
#include <hip/hip_runtime.h>
#include <hip/hip_bf16.h>
#include <stdint.h>

// ---------------- problem constants ----------------
constexpr int E   = 384;
constexpr int DFF = 1536;
constexpr int NH  = 6;
constexpr int HD  = 64;
constexpr int T   = 256;
constexpr int NL  = 6;
constexpr int NV  = 65;
constexpr int BB  = 128;
constexpr int MTOT = BB * T;           // 32768 rows
constexpr int CB  = 32;                // (kept for ws layout compatibility)

typedef __bf16 bf16;
typedef __attribute__((ext_vector_type(8))) __bf16 bf16x8;
typedef __attribute__((ext_vector_type(4))) float floatx4;

// ---------------- generic bf16 GEMM: C = A[M,K] @ W ----------------
// A staged via LDS (dist-2 reg->ds_write pipeline, 64B rows).
// B (weights) read DIRECT from global in fragment-swizzled layout:
//   Bf[((c16*nks + ks)*64 + lane)*8 + j] = W[ks*32 + (lane>>4)*8 + j][c16*16 + (lane&15)]
// -> one coalesced dwordx4 per fragment, prefetched 1 iter ahead. Halves LDS
// port pressure (the measured r13 limiter: 576 cyc LDS vs 78 cyc MFMA / iter).
// MODE 0: bf16 out (+bias, +relu, N-mask) | MODE 1: bf16 residual +=
// MODE 4: f32 out + N-mask | MODE 5: fused QKV split store (qk | vt)
#define GBM 128
#define GBN 128
#define GBK 32

template <int MODE>
__global__ __launch_bounds__(256) void k_gemm(
    const bf16* __restrict__ A, int lda,
    const bf16* __restrict__ Bf,              // fragment-layout weights
    const float* __restrict__ bias,
    void* __restrict__ Cv, void* __restrict__ Cv2, int ldc,
    int Mtiles, int Ntiles, int Nvalid, int K,
    int relu)
{
    __shared__ __align__(16) bf16 As[2 * GBM * GBK];   // 2 x 8 KB

    // XCD swizzle: all N-tiles of an M-tile land on one XCD's L2.
    int nb = gridDim.x;
    int per = nb >> 3;
    int bphys = blockIdx.x;
    int bid = (bphys & 7) * per + (bphys >> 3);

    int nt = bid % Ntiles;
    int mt = bid / Ntiles;

    const bf16* Ab = A + (long)mt * GBM * lda;

    int tid = threadIdx.x;
    int lane = tid & 63;
    int wid = tid >> 6;
    int wm = wid >> 1, wn = wid & 1;
    int lq = lane >> 4, lr = lane & 15;

    int srow = tid >> 2;            // 0..63
    int skc  = (tid & 3) * 8;       // k element offset 0,8,16,24

    const bf16* Arow = Ab + (long)srow * lda + skc;
    const long a2 = 64 * (long)lda;

    char* AsB = (char*)As;

    int nk = K / GBK;
    // B fragment base for this wave: c16base = nt*8 + wn*4
    const bf16* Bq = Bf + ((long)(nt * 8 + wn * 4) * nk) * 512 + lane * 8;

    floatx4 zero = {0.f, 0.f, 0.f, 0.f};
    floatx4 acc[4][4];
#pragma unroll
    for (int i = 0; i < 4; i++)
#pragma unroll
        for (int j = 0; j < 4; j++) acc[i][j] = zero;

    // prologue: A tile0 -> regs -> buf0; A tile1 -> regs; B frags for ki=0
    bf16x8 ra0 = *(const bf16x8*)(Arow);
    bf16x8 ra1 = *(const bf16x8*)(Arow + a2);
    *(bf16x8*)(AsB + tid * 16)        = ra0;
    *(bf16x8*)(AsB + 4096 + tid * 16) = ra1;
    if (nk > 1) {
        ra0 = *(const bf16x8*)(Arow + GBK);
        ra1 = *(const bf16x8*)(Arow + a2 + GBK);
    }
    bf16x8 bcur[4];
#pragma unroll
    for (int ni = 0; ni < 4; ni++)
        bcur[ni] = *(const bf16x8*)(Bq + (long)ni * nk * 512);
    __syncthreads();

    for (int ki = 0; ki < nk; ki++) {
        int ib = ki & 1;
        if (ki + 1 < nk) {
            char* An = AsB + (1 - ib) * 8192;
            *(bf16x8*)(An + tid * 16)        = ra0;
            *(bf16x8*)(An + 4096 + tid * 16) = ra1;
        }
        if (ki + 2 < nk) {
            int koff = (ki + 2) * GBK;
            ra0 = *(const bf16x8*)(Arow + koff);
            ra1 = *(const bf16x8*)(Arow + a2 + koff);
        }
        bf16x8 bnext[4];
        if (ki + 1 < nk) {
#pragma unroll
            for (int ni = 0; ni < 4; ni++)
                bnext[ni] = *(const bf16x8*)(Bq + ((long)ni * nk + ki + 1) * 512);
        }
        char* Ac = AsB + ib * 8192;

        bf16x8 af[4];
#pragma unroll
        for (int mi = 0; mi < 4; mi++)
            af[mi] = *(const bf16x8*)(Ac + ((wm * 64 + mi * 16 + lr) * GBK + lq * 8) * 2);
#pragma unroll
        for (int mi = 0; mi < 4; mi++)
#pragma unroll
            for (int ni = 0; ni < 4; ni++)
                acc[mi][ni] = __builtin_amdgcn_mfma_f32_16x16x32_bf16(
                    af[mi], bcur[ni], acc[mi][ni], 0, 0, 0);
#pragma unroll
        for (int ni = 0; ni < 4; ni++) bcur[ni] = bnext[ni];
        __syncthreads();
    }

    int m0 = mt * GBM, n0 = nt * GBN;
#pragma unroll
    for (int mi = 0; mi < 4; mi++) {
#pragma unroll
        for (int ni = 0; ni < 4; ni++) {
            int colL = n0 + wn * 64 + ni * 16 + lr;
#pragma unroll
            for (int r = 0; r < 4; r++) {
                int rowL = m0 + wm * 64 + mi * 16 + lq * 4 + r;
                float val = acc[mi][ni][r];
                if (MODE == 5) {
                    val += bias[colL];
                    if (colL < 768) {
                        bf16* Cp = (bf16*)Cv;
                        Cp[(long)rowL * 768 + colL] = (bf16)val;
                    } else {
                        bf16* Cp = (bf16*)Cv2;
                        long addr = (long)(rowL >> 8) * (E * T) + (long)(colL - 768) * T + (rowL & 255);
                        Cp[addr] = (bf16)val;
                    }
                } else if (MODE == 1) {
                    bf16* Cp = (bf16*)Cv;
                    long idx = (long)rowL * ldc + colL;
                    Cp[idx] = (bf16)((float)Cp[idx] + val + bias[colL]);
                } else if (MODE == 4) {
                    if (colL < Nvalid) {
                        float* Cp = (float*)Cv;
                        Cp[(long)rowL * ldc + colL] = val + bias[colL];
                    }
                } else {
                    if (colL < Nvalid) {
                        if (bias) val += bias[colL];
                        if (relu) val = fmaxf(val, 0.f);
                        bf16* Cp = (bf16*)Cv;
                        Cp[(long)rowL * ldc + colL] = (bf16)val;
                    }
                }
            }
        }
    }
}

// ---------------- fused causal attention (LDS-staged K/V) ----------------
__global__ __launch_bounds__(256) void k_attn(
    const bf16* __restrict__ qk, const bf16* __restrict__ vt,
    bf16* __restrict__ o)
{
    int nb = gridDim.x;
    int per = nb >> 3;
    int bphys = blockIdx.x;
    int bid = (bphys & 7) * per + (bphys >> 3);

    int qt = bid & 3; bid >>= 2;
    int h = bid % NH; int b = bid / NH;
    int tid = threadIdx.x;
    int lane = tid & 63;
    int w = tid >> 6;
    int lq = lane >> 4;     // 0..3
    int lr = lane & 15;

    __shared__ __align__(16) bf16 Ks[256 * 72];   // K rows padded; reused for P
    __shared__ __align__(16) bf16 Vs[64 * 264];   // V^T rows padded

    const bf16* qbase = qk + (long)(b * T + qt * 64 + w * 16) * 768 + h * 64;
    const bf16* kbase = qk + (long)(b * T) * 768 + 384 + h * 64;
    const bf16* vbase = vt + ((long)b * E + h * 64) * T;

#pragma unroll
    for (int i = 0; i < 8; i++) {
        int idx = i * 256 + tid;
        int row = idx >> 3, off = (idx & 7) * 8;
        *(bf16x8*)(&Ks[row * 72 + off]) = *(const bf16x8*)(kbase + (long)row * 768 + off);
    }
#pragma unroll
    for (int i = 0; i < 8; i++) {
        int idx = i * 256 + tid;
        int row = idx >> 5, off = (idx & 31) * 8;
        *(bf16x8*)(&Vs[row * 264 + off]) = *(const bf16x8*)(vbase + (long)row * 256 + off);
    }

    bf16x8 aq0 = *(const bf16x8*)(qbase + (long)lr * 768 + lq * 8);
    bf16x8 aq1 = *(const bf16x8*)(qbase + (long)lr * 768 + 32 + lq * 8);

    __syncthreads();

    const int ntmax = qt * 4 + 3;
    floatx4 zero = {0.f, 0.f, 0.f, 0.f};
    floatx4 s[16];
#pragma unroll
    for (int nt = 0; nt < 16; nt++) s[nt] = zero;

#pragma unroll
    for (int nt = 0; nt < 16; nt++) {
        if (nt <= ntmax) {
            const bf16* kp = &Ks[(nt * 16 + lr) * 72 + lq * 8];
            bf16x8 b0 = *(const bf16x8*)(kp);
            bf16x8 b1 = *(const bf16x8*)(kp + 32);
            s[nt] = __builtin_amdgcn_mfma_f32_16x16x32_bf16(aq0, b0, s[nt], 0, 0, 0);
            s[nt] = __builtin_amdgcn_mfma_f32_16x16x32_bf16(aq1, b1, s[nt], 0, 0, 0);
        }
    }

    int trow0 = qt * 64 + w * 16 + lq * 4;
    float m4[4] = {-3e38f, -3e38f, -3e38f, -3e38f};
#pragma unroll
    for (int nt = 0; nt < 16; nt++) {
        if (nt <= ntmax) {
            int tc = nt * 16 + lr;
#pragma unroll
            for (int r = 0; r < 4; r++) {
                float v = s[nt][r] * 0.125f;
                if (tc > trow0 + r) v = -3e38f;
                s[nt][r] = v;
                m4[r] = fmaxf(m4[r], v);
            }
        }
    }
#pragma unroll
    for (int r = 0; r < 4; r++) {
#pragma unroll
        for (int off = 1; off < 16; off <<= 1)
            m4[r] = fmaxf(m4[r], __shfl_xor(m4[r], off, 64));
    }

    float l4[4] = {0.f, 0.f, 0.f, 0.f};
#pragma unroll
    for (int nt = 0; nt < 16; nt++) {
        if (nt <= ntmax) {
#pragma unroll
            for (int r = 0; r < 4; r++) {
                float pv = __expf(s[nt][r] - m4[r]);
                l4[r] += pv;
                s[nt][r] = pv;
            }
        }
    }
#pragma unroll
    for (int r = 0; r < 4; r++) {
#pragma unroll
        for (int off = 1; off < 16; off <<= 1)
            l4[r] += __shfl_xor(l4[r], off, 64);
    }

    __syncthreads();   // Ks fully consumed -> reuse for P

    bf16* P = Ks + w * (16 * 264);
#pragma unroll
    for (int nt = 0; nt < 16; nt++) {
        if (nt <= ntmax) {
#pragma unroll
            for (int r = 0; r < 4; r++)
                P[(lq * 4 + r) * 264 + nt * 16 + lr] = (bf16)s[nt][r];
        }
    }

    floatx4 oacc[4];
#pragma unroll
    for (int nd = 0; nd < 4; nd++) oacc[nd] = zero;
    const int kkmax = 2 * (qt + 1);
#pragma unroll
    for (int kk = 0; kk < 8; kk++) {
        if (kk < kkmax) {
            bf16x8 ap = *(const bf16x8*)(&P[lr * 264 + kk * 32 + lq * 8]);
#pragma unroll
            for (int nd = 0; nd < 4; nd++) {
                bf16x8 bv = *(const bf16x8*)(&Vs[(nd * 16 + lr) * 264 + kk * 32 + lq * 8]);
                oacc[nd] = __builtin_amdgcn_mfma_f32_16x16x32_bf16(ap, bv, oacc[nd], 0, 0, 0);
            }
        }
    }

#pragma unroll
    for (int r = 0; r < 4; r++) {
        float inv = 1.0f / l4[r];
        long rowg = (long)b * T + trow0 + r;
#pragma unroll
        for (int nd = 0; nd < 4; nd++) {
            o[rowg * E + h * 64 + nd * 16 + lr] = (bf16)(oacc[nd][r] * inv);
        }
    }
}

// ---------------- layernorm: bf16 in -> bf16 out (wave per row) ----------------
__global__ void k_ln(const bf16* __restrict__ x, const float* __restrict__ g,
                     const float* __restrict__ b, bf16* __restrict__ h) {
    int row = blockIdx.x * 4 + (threadIdx.x >> 6);
    int lane = threadIdx.x & 63;
    const bf16* xr = x + (long)row * E;
    float v[6];
    float s = 0.f;
#pragma unroll
    for (int i = 0; i < 6; i++) { v[i] = (float)xr[lane + 64 * i]; s += v[i]; }
#pragma unroll
    for (int o = 1; o < 64; o <<= 1) s += __shfl_xor(s, o, 64);
    float mu = s * (1.0f / E);
    float q = 0.f;
#pragma unroll
    for (int i = 0; i < 6; i++) { float d = v[i] - mu; q += d * d; }
#pragma unroll
    for (int o = 1; o < 64; o <<= 1) q += __shfl_xor(q, o, 64);
    float rs = rsqrtf(q * (1.0f / E) + 1e-5f);
    bf16* hr = h + (long)row * E;
#pragma unroll
    for (int i = 0; i < 6; i++) {
        int c = lane + 64 * i;
        hr[c] = (bf16)((v[i] - mu) * rs * g[c] + b[c]);
    }
}

// ---------------- fragment-layout weight transpose ----------------
// W [L][K][N] (f32) -> Wf [L][NPAD/16][K/32][64][8] (bf16), cols>=N zero.
// Wf[((c16*nks + ks)*64 + lane)*8 + j] = W[ks*32 + (lane>>4)*8 + j][c16*16 + (lane&15)]
__global__ void k_transpose_frag(const float* __restrict__ W, bf16* __restrict__ Wf,
                                 int K, int N, int NPAD) {
    long idx = (long)blockIdx.x * 256 + threadIdx.x;   // over NL*NPAD*K
    long per = (long)NPAD * K;
    int l = (int)(idx / per);
    long r = idx - (long)l * per;
    int j = (int)(r & 7); r >>= 3;
    int lane = (int)(r & 63); r >>= 6;
    int nks = K / 32;
    int ks = (int)(r % nks);
    int c16 = (int)(r / nks);
    int col = c16 * 16 + (lane & 15);
    int k = ks * 32 + (lane >> 4) * 8 + j;
    Wf[idx] = (col < N) ? (bf16)W[((long)l * K + k) * N + col] : (bf16)0.0f;
}

// ---------------- fragment-layout fused QKV transpose: [L] cols 0..1151 ----------------
__global__ void k_transpose_qkv_frag(const float* __restrict__ Wq, const float* __restrict__ Wk,
                                     const float* __restrict__ Wv, bf16* __restrict__ Wf) {
    long idx = (long)blockIdx.x * 256 + threadIdx.x;   // over NL*1152*384
    long per = (long)1152 * E;
    int l = (int)(idx / per);
    long r = idx - (long)l * per;
    int j = (int)(r & 7); r >>= 3;
    int lane = (int)(r & 63); r >>= 6;
    int nks = E / 32;                                   // 12
    int ks = (int)(r % nks);
    int c16 = (int)(r / nks);
    int col = c16 * 16 + (lane & 15);                   // 0..1151
    int k = ks * 32 + (lane >> 4) * 8 + j;
    const float* src;
    int cc;
    if (col < 384)      { src = Wq; cc = col; }
    else if (col < 768) { src = Wk; cc = col - 384; }
    else                { src = Wv; cc = col - 768; }
    Wf[idx] = (bf16)src[((long)l * E + k) * E + cc];
}

// ---------------- fused QKV bias concat: [L][1152] f32 ----------------
__global__ void k_bias_qkv(const float* __restrict__ bq, const float* __restrict__ bk,
                           const float* __restrict__ bv, float* __restrict__ bqkv) {
    int idx = blockIdx.x * 256 + threadIdx.x;
    int l = idx / 1152;
    int j = idx - l * 1152;
    const float* src;
    int jj;
    if (j < 384)      { src = bq; jj = j; }
    else if (j < 768) { src = bk; jj = j - 384; }
    else              { src = bv; jj = j - 768; }
    bqkv[idx] = src[l * E + jj];
}

// ---------------- embedding + positional -> bf16 residual ----------------
__global__ void k_embed(const int* __restrict__ tokens, const float* __restrict__ pos,
                        const float* __restrict__ emb, bf16* __restrict__ x) {
    long idx = (long)blockIdx.x * 256 + threadIdx.x;
    int e = (int)(idx % E);
    long bt = idx / E;
    int t = (int)(bt % T);
    int tok = tokens[bt];
    x[idx] = (bf16)(emb[(long)tok * E + e] + pos[(long)t * E + e]);
}

// ---------------- launcher ----------------
extern "C" void kernel_launch(void* const* d_in, const int* in_sizes, int n_in,
                              void* d_out, int out_size, void* d_ws, size_t ws_size,
                              hipStream_t stream) {
    const int*   tokens = (const int*)d_in[0];
    const float* pos  = (const float*)d_in[1];
    const float* emb  = (const float*)d_in[2];
    const float* Wq   = (const float*)d_in[3];
    const float* bq   = (const float*)d_in[4];
    const float* Wk   = (const float*)d_in[5];
    const float* bk   = (const float*)d_in[6];
    const float* Wv   = (const float*)d_in[7];
    const float* bv   = (const float*)d_in[8];
    const float* Wo   = (const float*)d_in[9];
    const float* bo   = (const float*)d_in[10];
    const float* g1   = (const float*)d_in[11];
    const float* be1  = (const float*)d_in[12];
    const float* W1   = (const float*)d_in[13];
    const float* c1   = (const float*)d_in[14];
    const float* W2   = (const float*)d_in[15];
    const float* c2   = (const float*)d_in[16];
    const float* g2   = (const float*)d_in[17];
    const float* be2  = (const float*)d_in[18];
    const float* Wl   = (const float*)d_in[19];
    const float* bl   = (const float*)d_in[20];

    // ---- workspace layout (~173 MB peak) ----
    char* p = (char*)d_ws;
    bf16* x  = (bf16*)p;   p += (long)MTOT * E * 2;          // residual (bf16)
    bf16* h  = (bf16*)p;   p += (long)MTOT * E * 2;          // LN out / o (alias)
    bf16* qk = (bf16*)p;   p += (long)MTOT * 768 * 2;        // fused Q|K
    bf16* vt = (bf16*)p;   p += (long)BB * E * T * 2;        // V^T per (seq,head)
    bf16* SP = (bf16*)p;   p += (long)CB * NH * T * T * 2;   // kept only for mid alias span
    bf16* WqkvF = (bf16*)p; p += (long)NL * 1152 * E * 2;    // fragment layouts
    bf16* WoF = (bf16*)p;  p += (long)NL * E * E * 2;
    bf16* W1F = (bf16*)p;  p += (long)NL * DFF * E * 2;
    bf16* W2F = (bf16*)p;  p += (long)NL * E * DFF * 2;
    bf16* WlF = (bf16*)p;  p += (long)128 * E * 2;
    float* bqkv = (float*)p; p += (long)NL * 1152 * 4;
    bf16* mid = qk;          // alias: qk+vt+SP = 100.66 MB = MTOT*DFF*2 exactly
    bf16* o   = h;
    (void)SP;

    // ---- setup (once per call) ----
    k_transpose_qkv_frag<<<(NL * 1152 * E) / 256, 256, 0, stream>>>(Wq, Wk, Wv, WqkvF);
    k_transpose_frag<<<(NL * E * E) / 256, 256, 0, stream>>>(Wo, WoF, E, E, E);
    k_transpose_frag<<<(NL * DFF * E) / 256, 256, 0, stream>>>(W1, W1F, E, DFF, DFF);
    k_transpose_frag<<<(NL * E * DFF) / 256, 256, 0, stream>>>(W2, W2F, DFF, E, E);
    k_transpose_frag<<<(128 * E) / 256, 256, 0, stream>>>(Wl, WlF, E, NV, 128);
    k_bias_qkv<<<(NL * 1152) / 256, 256, 0, stream>>>(bq, bk, bv, bqkv);

    // ---- embedding ----
    k_embed<<<(MTOT * E) / 256, 256, 0, stream>>>(tokens, pos, emb, x);

    for (int l = 0; l < NL; l++) {
        // LN1
        k_ln<<<MTOT / 4, 256, 0, stream>>>(x, g1 + l * E, be1 + l * E, h);
        // fused QKV: M=32768, N=1152, K=384
        k_gemm<5><<<256 * 9, 256, 0, stream>>>(h, E, WqkvF + (long)l * 1152 * E,
                                               bqkv + l * 1152, qk, vt, 0,
                                               256, 9, 1152, E, 0);
        // fused causal attention
        k_attn<<<BB * NH * 4, 256, 0, stream>>>(qk, vt, o);
        // x += O @ Wo + bo
        k_gemm<1><<<256 * 3, 256, 0, stream>>>(o, E, WoF + (long)l * E * E,
                                               bo + l * E, x, nullptr, E,
                                               256, 3, E, E, 0);
        // LN2
        k_ln<<<MTOT / 4, 256, 0, stream>>>(x, g2 + l * E, be2 + l * E, h);
        // mid = relu(h @ W1 + c1)
        k_gemm<0><<<256 * 12, 256, 0, stream>>>(h, E, W1F + (long)l * DFF * E,
                                                c1 + l * DFF, mid, nullptr, DFF,
                                                256, 12, DFF, E, 1);
        // x += mid @ W2 + c2
        k_gemm<1><<<256 * 3, 256, 0, stream>>>(mid, DFF, W2F + (long)l * E * DFF,
                                               c2 + l * E, x, nullptr, E,
                                               256, 3, E, DFF, 0);
    }

    // logits = x @ Wl + bl  (N=65 masked from 128), f32 out
    k_gemm<4><<<256 * 1, 256, 0, stream>>>(x, E, WlF,
                                           bl, d_out, nullptr, NV,
                                           256, 1, NV, E, 0);
}